// Round 21
// baseline (353.692 us; speedup 1.0000x reference)
//
#include <hip/hip_runtime.h>
#include <hip/hip_bf16.h>

typedef _Float16 f16;
typedef _Float16 f16x2 __attribute__((ext_vector_type(2)));
typedef _Float16 f16x4 __attribute__((ext_vector_type(4)));
typedef _Float16 f16x8 __attribute__((ext_vector_type(8)));
typedef float f32x4 __attribute__((ext_vector_type(4)));

#define L_SEQ 2048
#define DIM 3072
#define NHEAD 24
#define HDIM 128

// async global->LDS, 16B per lane. LDS dest must be wave-uniform base (+lane*16 implicit).
__device__ __forceinline__ void gll16(const f16* g, f16* l) {
    __builtin_amdgcn_global_load_lds((const __attribute__((address_space(1))) void*)g,
                                     (__attribute__((address_space(3))) void*)l, 16, 0, 0);
}

// ---------------- merged f32 -> f16 conversion (3 regions, 1 launch) --------
__global__ __launch_bounds__(256) void cvt3_kernel(const float* __restrict__ s0, f16* __restrict__ d0, int n0,
                                                   const float* __restrict__ s1, f16* __restrict__ d1, int n1,
                                                   const float* __restrict__ s2, f16* __restrict__ d2, int n2) {
    int i = blockIdx.x * blockDim.x + threadIdx.x;
    int stride = gridDim.x * blockDim.x;
    for (int j = i; j < n0; j += stride) {
        float4 v = reinterpret_cast<const float4*>(s0)[j];
        f16x4 o = {(f16)v.x, (f16)v.y, (f16)v.z, (f16)v.w};
        reinterpret_cast<f16x4*>(d0)[j] = o;
    }
    for (int j = i; j < n1; j += stride) {
        float4 v = reinterpret_cast<const float4*>(s1)[j];
        f16x4 o = {(f16)v.x, (f16)v.y, (f16)v.z, (f16)v.w};
        reinterpret_cast<f16x4*>(d1)[j] = o;
    }
    for (int j = i; j < n2; j += stride) {
        float4 v = reinterpret_cast<const float4*>(s2)[j];
        f16x4 o = {(f16)v.x, (f16)v.y, (f16)v.z, (f16)v.w};
        reinterpret_cast<f16x4*>(d2)[j] = o;
    }
}

// ---------------- 256x128-tile ring-3 NT GEMM (R5 structure: best qkv) ------
// BK=32, 3-slot LDS ring (72 KB -> 2 blocks/CU), counted vmcnt(3) (T4),
// zero-conflict XOR swizzle (T2), setprio (T5), 2D-chunked XCD swizzle (T1).
// 512 thr, 8 waves (4x2) of 64x64. q,k cols -> f16 C; v cols -> vT[hd][l].
#define GEMM_BODY_L(T, VM, DO_STAGE)                                                    \
    {                                                                                   \
        asm volatile("s_waitcnt vmcnt(" #VM ")" ::: "memory");                          \
        __builtin_amdgcn_s_barrier();                                                   \
        __builtin_amdgcn_sched_barrier(0);                                              \
        const int slot_ = (T) % 3;                                                      \
        f16x8 af[4], bf[4];                                                             \
        _Pragma("unroll") for (int i = 0; i < 4; i++)                                   \
            af[i] = *reinterpret_cast<const f16x8*>(                                    \
                &As[slot_][(wr + i * 16 + laneM) * 32 + fc16]);                         \
        _Pragma("unroll") for (int j = 0; j < 4; j++)                                   \
            bf[j] = *reinterpret_cast<const f16x8*>(                                    \
                &Bs[slot_][(wc + j * 16 + laneM) * 32 + fc16]);                         \
        if (DO_STAGE) {                                                                 \
            const int t2 = (T) + 2;                                                     \
            const int s2 = t2 % 3;                                                      \
            gll16(Asrc0 + t2 * 32, &As[s2][dstoff]);                                    \
            gll16(Asrc1 + t2 * 32, &As[s2][4096 + dstoff]);                             \
            gll16(Bsrc + t2 * 32, &Bs[s2][dstoff]);                                     \
        }                                                                               \
        __builtin_amdgcn_s_setprio(1);                                                  \
        _Pragma("unroll") for (int i = 0; i < 4; i++)                                   \
            _Pragma("unroll") for (int j = 0; j < 4; j++)                               \
                acc[i][j] =                                                             \
                    __builtin_amdgcn_mfma_f32_16x16x32_f16(af[i], bf[j], acc[i][j],     \
                                                           0, 0, 0);                    \
        __builtin_amdgcn_s_setprio(0);                                                  \
    }

__global__ __launch_bounds__(512, 4) void qkv_gemm(const f16* __restrict__ A,
                                                   const f16* __restrict__ B,
                                                   f16* __restrict__ Cf16,
                                                   f16* __restrict__ vT,
                                                   int M, int N, int K) {
    __shared__ f16 As[3][256 * 32];   // 3 x 16 KB
    __shared__ f16 Bs[3][128 * 32];   // 3 x 8 KB
    const int tid = threadIdx.x;
    const int wid = tid >> 6;
    const int lane = tid & 63;
    const int grp = lane >> 4;
    const int laneM = lane & 15;

    // T1: bijective XCD chunk; by (M) fastest -> co-resident blocks share B in L2.
    const int nwg = gridDim.x * gridDim.y;   // 72*8 = 576, %8 == 0
    const int orig = blockIdx.y * gridDim.x + blockIdx.x;
    const int wgid = (orig & 7) * (nwg >> 3) + (orig >> 3);
    const int by = wgid % gridDim.y;
    const int bx = wgid / gridDim.y;
    const int m0 = by * 256;
    const int n0 = bx * 128;

    const int wr = (wid >> 1) * 64;   // wave row base (4 M-groups)
    const int wc = (wid & 1) * 64;    // wave col base (2 N-groups)
    const int NT = K >> 5;
    const int fc16 = (grp ^ ((laneM >> 1) & 3)) * 8;  // swizzled read col (f16 units)

    // staging: per K-tile 3 gll issues (A rows 0-127, A rows 128-255, B rows 0-127)
    const int srow = tid >> 2;                               // 0..127
    const int scol = (((tid & 3) ^ ((tid >> 3) & 3)) << 3);  // pre-swizzled source col
    const f16* Asrc0 = A + (size_t)(m0 + srow) * K + scol;
    const f16* Asrc1 = A + (size_t)(m0 + 128 + srow) * K + scol;
    const f16* Bsrc = B + (size_t)(n0 + srow) * K + scol;
    const int dstoff = wid * 512;  // per-wave 1KB slice within an 8KB issue (f16)

    const f32x4 vzero = {0.f, 0.f, 0.f, 0.f};
    f32x4 acc[4][4];
#pragma unroll
    for (int i = 0; i < 4; i++)
#pragma unroll
        for (int j = 0; j < 4; j++) acc[i][j] = vzero;

    // prologue: stage tiles 0,1
#pragma unroll
    for (int t = 0; t < 2; t++) {
        gll16(Asrc0 + t * 32, &As[t][dstoff]);
        gll16(Asrc1 + t * 32, &As[t][4096 + dstoff]);
        gll16(Bsrc + t * 32, &Bs[t][dstoff]);
    }

    int t = 0;
    for (; t < NT - 2; ++t) GEMM_BODY_L(t, 3, true);
    GEMM_BODY_L(t, 3, false); ++t;
    GEMM_BODY_L(t, 0, false);

    // epilogue: C/D layout col = laneM, row = grp*4 + r (verified m89)
    if (n0 < 2 * DIM) {
#pragma unroll
        for (int i = 0; i < 4; i++)
#pragma unroll
            for (int j = 0; j < 4; j++)
#pragma unroll
                for (int r = 0; r < 4; r++) {
                    int row = m0 + wr + i * 16 + grp * 4 + r;
                    int col = n0 + wc + j * 16 + laneM;
                    Cf16[(size_t)row * N + col] = (f16)acc[i][j][r];
                }
    } else {
        // v columns: fused transpose -> vT[hd][l], 4 consecutive l per lane (8B)
#pragma unroll
        for (int i = 0; i < 4; i++)
#pragma unroll
            for (int j = 0; j < 4; j++) {
                int hd = n0 - 2 * DIM + wc + j * 16 + laneM;
                int row0 = m0 + wr + i * 16 + grp * 4;
                f16x4 pk;
#pragma unroll
                for (int r = 0; r < 4; r++) pk[r] = (f16)acc[i][j][r];
                *reinterpret_cast<f16x4*>(&vT[(size_t)hd * L_SEQ + row0]) = pk;
            }
    }
}

// ---------------- 128x128-tile ring-3 NT GEMM (proj: best small-grid) -------
#define GEMM_BODY_S(T, VM, DO_STAGE)                                                    \
    {                                                                                   \
        asm volatile("s_waitcnt vmcnt(" #VM ")" ::: "memory");                          \
        __builtin_amdgcn_s_barrier();                                                   \
        __builtin_amdgcn_sched_barrier(0);                                              \
        const int slot_ = (T) % 3;                                                      \
        f16x8 af[4], bf[4];                                                             \
        _Pragma("unroll") for (int i = 0; i < 4; i++)                                   \
            af[i] = *reinterpret_cast<const f16x8*>(                                    \
                &As[slot_][(wr + i * 16 + laneM) * 32 + fc16]);                         \
        _Pragma("unroll") for (int j = 0; j < 4; j++)                                   \
            bf[j] = *reinterpret_cast<const f16x8*>(                                    \
                &Bs[slot_][(wc + j * 16 + laneM) * 32 + fc16]);                         \
        if (DO_STAGE) {                                                                 \
            const int t2 = (T) + 2;                                                     \
            const int s2 = t2 % 3;                                                      \
            gll16(Asrc + t2 * 32, &As[s2][dstoff]);                                     \
            gll16(Asrc + (size_t)64 * K + t2 * 32, &As[s2][2048 + dstoff]);             \
            gll16(Bsrc + t2 * 32, &Bs[s2][dstoff]);                                     \
            gll16(Bsrc + (size_t)64 * K + t2 * 32, &Bs[s2][2048 + dstoff]);             \
        }                                                                               \
        __builtin_amdgcn_s_setprio(1);                                                  \
        _Pragma("unroll") for (int i = 0; i < 4; i++)                                   \
            _Pragma("unroll") for (int j = 0; j < 4; j++)                               \
                acc[i][j] =                                                             \
                    __builtin_amdgcn_mfma_f32_16x16x32_f16(af[i], bf[j], acc[i][j],     \
                                                           0, 0, 0);                    \
        __builtin_amdgcn_s_setprio(0);                                                  \
    }

__global__ __launch_bounds__(256, 4) void proj_gemm(const f16* __restrict__ A,
                                                    const f16* __restrict__ B,
                                                    float* __restrict__ Cf32,
                                                    const float* __restrict__ bias,
                                                    int M, int N, int K) {
    __shared__ f16 As[3][128 * 32];   // 3 x 8 KB
    __shared__ f16 Bs[3][128 * 32];   // 3 x 8 KB
    const int tid = threadIdx.x;
    const int wid = tid >> 6;
    const int lane = tid & 63;
    const int grp = lane >> 4;
    const int laneM = lane & 15;

    const int nwg = gridDim.x * gridDim.y;
    const int orig = blockIdx.y * gridDim.x + blockIdx.x;
    const int wgid = (orig & 7) * (nwg >> 3) + (orig >> 3);
    const int by = wgid % gridDim.y;
    const int bx = wgid / gridDim.y;
    const int m0 = by * 128;
    const int n0 = bx * 128;

    const int wr = (wid >> 1) * 64;
    const int wc = (wid & 1) * 64;
    const int NT = K >> 5;
    const int fc16 = (grp ^ ((laneM >> 1) & 3)) * 8;

    const int srow = tid >> 2;
    const int scol = (((tid & 3) ^ ((tid >> 3) & 3)) << 3);
    const f16* Asrc = A + (size_t)(m0 + srow) * K + scol;
    const f16* Bsrc = B + (size_t)(n0 + srow) * K + scol;
    const int dstoff = wid * 512;

    const f32x4 vzero = {0.f, 0.f, 0.f, 0.f};
    f32x4 acc[4][4];
#pragma unroll
    for (int i = 0; i < 4; i++)
#pragma unroll
        for (int j = 0; j < 4; j++) acc[i][j] = vzero;

#pragma unroll
    for (int t = 0; t < 2; t++) {
        gll16(Asrc + t * 32, &As[t][dstoff]);
        gll16(Asrc + (size_t)64 * K + t * 32, &As[t][2048 + dstoff]);
        gll16(Bsrc + t * 32, &Bs[t][dstoff]);
        gll16(Bsrc + (size_t)64 * K + t * 32, &Bs[t][2048 + dstoff]);
    }

    int t = 0;
    for (; t < NT - 2; ++t) GEMM_BODY_S(t, 4, true);
    GEMM_BODY_S(t, 4, false); ++t;
    GEMM_BODY_S(t, 0, false);

#pragma unroll
    for (int i = 0; i < 4; i++)
#pragma unroll
        for (int j = 0; j < 4; j++)
#pragma unroll
            for (int r = 0; r < 4; r++) {
                int row = m0 + wr + i * 16 + grp * 4 + r;
                int col = n0 + wc + j * 16 + laneM;
                Cf32[(size_t)row * N + col] = acc[i][j][r] + bias[col];
            }
}

// ---------------- fused RMSNorm + RoPE for q,k (4 waves = 4 heads/block) ----
__global__ __launch_bounds__(256) void fuse_qk_kernel(const f16* __restrict__ qkv,
                                                      const float* __restrict__ pe,
                                                      const float* __restrict__ qs,
                                                      const float* __restrict__ ks,
                                                      f16* __restrict__ qb,
                                                      f16* __restrict__ kb) {
    const int l = blockIdx.x;
    const int h = blockIdx.y * 4 + (threadIdx.x >> 6);
    const int i = threadIdx.x & 63;
    const f16* row = qkv + (size_t)l * (3 * DIM) + h * HDIM;
    f16x2 qp = *reinterpret_cast<const f16x2*>(row + 2 * i);
    f16x2 kp = *reinterpret_cast<const f16x2*>(row + DIM + 2 * i);
    float q0 = (float)qp[0], q1 = (float)qp[1];
    float k0 = (float)kp[0], k1 = (float)kp[1];
    float sq = q0 * q0 + q1 * q1;
    float sk = k0 * k0 + k1 * k1;
#pragma unroll
    for (int off = 1; off < 64; off <<= 1) {
        sq += __shfl_xor(sq, off);
        sk += __shfl_xor(sk, off);
    }
    const float SCALE = 0.08838834764831845f;  // 1/sqrt(128), folded into q
    float rq = rsqrtf(sq * (1.0f / 128.0f) + 1e-6f) * SCALE;
    float rk = rsqrtf(sk * (1.0f / 128.0f) + 1e-6f);
    float4 w = *reinterpret_cast<const float4*>(pe + ((size_t)l * 64 + i) * 4);
    float qa = q0 * rq * qs[2 * i];
    float qbv = q1 * rq * qs[2 * i + 1];
    float ka = k0 * rk * ks[2 * i];
    float kbv = k1 * rk * ks[2 * i + 1];
    f16x2 qo = {(f16)(w.x * qa + w.y * qbv), (f16)(w.z * qa + w.w * qbv)};
    f16x2 ko = {(f16)(w.x * ka + w.y * kbv), (f16)(w.z * ka + w.w * kbv)};
    *reinterpret_cast<f16x2*>(qb + ((size_t)h * L_SEQ + l) * HDIM + 2 * i) = qo;
    *reinterpret_cast<f16x2*>(kb + ((size_t)h * L_SEQ + l) * HDIM + 2 * i) = ko;
}

// ---------------- flash attention v2: 32 q-rows per wave (R20-proven) -------
#define KVBLK 64
#define NSTEP (L_SEQ / KVBLK)

__device__ __forceinline__ void stage_kv(const f16* __restrict__ Kh,
                                         const f16* __restrict__ Vh,
                                         int k0, f16* Kt, f16* Vt, int tid) {
    const int wid = tid >> 6;
    const int krow = tid >> 4;
    const int kcl = (tid & 15) ^ (krow & 7);
    const int vrow = tid >> 3;
    const int vcl = (tid & 7) ^ (vrow & 7);
#pragma unroll
    for (int i = 0; i < 4; i++)
        gll16(Kh + (size_t)(k0 + i * 16 + krow) * HDIM + kcl * 8, Kt + i * 2048 + wid * 512);
#pragma unroll
    for (int i = 0; i < 4; i++)
        gll16(Vh + (size_t)(i * 32 + vrow) * L_SEQ + k0 + vcl * 8, Vt + i * 2048 + wid * 512);
}

__global__ __launch_bounds__(256, 2) void attn_kernel(const f16* __restrict__ qb,
                                                      const f16* __restrict__ kb,
                                                      const f16* __restrict__ vT,
                                                      f16* __restrict__ attnb) {
    __shared__ f16 Kt[2][64 * 128];   // 2 x 16 KB
    __shared__ f16 Vt[2][128 * 64];   // 2 x 16 KB
    __shared__ f16 Pl[4][16 * 72];    // per-wave P tile (reused for both groups)
    const int tid = threadIdx.x;
    const int wid = tid >> 6;
    const int lane = tid & 63;
    const int grp = lane >> 4;
    const int laneM = lane & 15;

    // T1: bijective XCD chunk (nwg = 384, %8 == 0). Same-head blocks cluster.
    const int nwg = gridDim.x * gridDim.y;
    const int orig = blockIdx.y * gridDim.x + blockIdx.x;
    const int wgid = (orig & 7) * (nwg >> 3) + (orig >> 3);
    const int h = wgid / gridDim.x;
    const int q0 = (wgid % gridDim.x) * 128 + wid * 32;   // 32 q-rows per wave

    const f16* Qh = qb + (size_t)h * L_SEQ * HDIM;
    const f16* Kh = kb + (size_t)h * L_SEQ * HDIM;
    const f16* Vh = vT + (size_t)h * HDIM * L_SEQ;

    f16x8 qf[2][4];
#pragma unroll
    for (int g = 0; g < 2; g++)
#pragma unroll
        for (int c = 0; c < 4; c++)
            qf[g][c] = *reinterpret_cast<const f16x8*>(
                Qh + (size_t)(q0 + g * 16 + laneM) * HDIM + c * 32 + grp * 8);

    const f32x4 vzero = {0.f, 0.f, 0.f, 0.f};
    f32x4 O[2][8];
#pragma unroll
    for (int g = 0; g < 2; g++)
#pragma unroll
        for (int f = 0; f < 8; f++) O[g][f] = vzero;
    float m[2] = {-3.0e38f, -3.0e38f};
    float lsum[2] = {0.f, 0.f};
    f16* Prow = &Pl[wid][laneM * 72];
    const int swz = laneM & 7;

    stage_kv(Kh, Vh, 0, Kt[0], Vt[0], tid);

    for (int step = 0; step < NSTEP; ++step) {
        const int cur = step & 1;
        __syncthreads();
        if (step + 1 < NSTEP)
            stage_kv(Kh, Vh, (step + 1) * KVBLK, Kt[cur ^ 1], Vt[cur ^ 1], tid);
        const f16* Kc = Kt[cur];
        const f16* Vc = Vt[cur];

        f32x4 s[2][4];
#pragma unroll
        for (int g = 0; g < 2; g++)
#pragma unroll
            for (int cc = 0; cc < 4; cc++) s[g][cc] = vzero;
#pragma unroll
        for (int cc = 0; cc < 4; cc++) {
            f16x8 kf[4];
#pragma unroll
            for (int c = 0; c < 4; c++)
                kf[c] = *reinterpret_cast<const f16x8*>(
                    &Kc[(cc * 16 + laneM) * 128 + (((c * 4 + grp) ^ swz) * 8)]);
#pragma unroll
            for (int c = 0; c < 4; c++) {
                s[0][cc] = __builtin_amdgcn_mfma_f32_16x16x32_f16(kf[c], qf[0][c], s[0][cc], 0, 0, 0);
                s[1][cc] = __builtin_amdgcn_mfma_f32_16x16x32_f16(kf[c], qf[1][c], s[1][cc], 0, 0, 0);
            }
        }

#pragma unroll
        for (int g = 0; g < 2; g++) {
            float pmax = s[g][0][0];
#pragma unroll
            for (int cc = 0; cc < 4; cc++)
#pragma unroll
                for (int r = 0; r < 4; r++) pmax = fmaxf(pmax, s[g][cc][r]);
            if (!__all(pmax <= m[g] + 8.0f)) {  // defer-max
                float pm = fmaxf(pmax, __shfl_xor(pmax, 16));
                pm = fmaxf(pm, __shfl_xor(pm, 32));
                float mnew = fmaxf(m[g], pm);
                float alpha = __expf(m[g] - mnew);
                m[g] = mnew;
                lsum[g] *= alpha;
                float af[4];
#pragma unroll
                for (int r = 0; r < 4; r++) af[r] = __shfl(alpha, grp * 4 + r);
#pragma unroll
                for (int f = 0; f < 8; f++)
#pragma unroll
                    for (int r = 0; r < 4; r++) O[g][f][r] *= af[r];
            }
            float ps = 0.f;
#pragma unroll
            for (int cc = 0; cc < 4; cc++) {
                f16x4 pk;
#pragma unroll
                for (int r = 0; r < 4; r++) {
                    float p = __expf(s[g][cc][r] - m[g]);
                    ps += p;
                    pk[r] = (f16)p;
                }
                *reinterpret_cast<f16x4*>(Prow + cc * 16 + grp * 4) = pk;
            }
            ps += __shfl_xor(ps, 16);
            ps += __shfl_xor(ps, 32);
            lsum[g] += ps;

#pragma unroll
            for (int z = 0; z < 2; z++) {
                f16x8 pa = *reinterpret_cast<const f16x8*>(Prow + z * 32 + grp * 8);
#pragma unroll
                for (int f = 0; f < 8; f++) {
                    f16x8 vf = *reinterpret_cast<const f16x8*>(
                        &Vc[(f * 16 + laneM) * 64 + (((z * 4 + grp) ^ swz) * 8)]);
                    O[g][f] = __builtin_amdgcn_mfma_f32_16x16x32_f16(pa, vf, O[g][f], 0, 0, 0);
                }
            }
        }
    }

#pragma unroll
    for (int g = 0; g < 2; g++) {
        float li = 1.0f / lsum[g];
        float lf[4];
#pragma unroll
        for (int r = 0; r < 4; r++) lf[r] = __shfl(li, grp * 4 + r);
#pragma unroll
        for (int f = 0; f < 8; f++)
#pragma unroll
            for (int r = 0; r < 4; r++) {
                int row = q0 + g * 16 + grp * 4 + r;
                attnb[(size_t)row * DIM + h * HDIM + f * 16 + laneM] = (f16)(O[g][f][r] * lf[r]);
            }
    }
}

extern "C" void kernel_launch(void* const* d_in, const int* in_sizes, int n_in,
                              void* d_out, int out_size, void* d_ws, size_t ws_size,
                              hipStream_t stream) {
    const float* x = (const float*)d_in[0];
    const float* pe = (const float*)d_in[1];
    const float* w_qkv = (const float*)d_in[2];
    const float* w_proj = (const float*)d_in[3];
    const float* b_proj = (const float*)d_in[4];
    const float* q_scale = (const float*)d_in[5];
    const float* k_scale = (const float*)d_in[6];
    float* out = (float*)d_out;

    char* ws = (char*)d_ws;
    f16* xb     = (f16*)(ws + 0);           // 2048*3072
    f16* wqkvb  = (f16*)(ws + 12582912);    // 9216*3072
    f16* wprojb = (f16*)(ws + 69206016);    // 3072*3072
    f16* qkvb   = (f16*)(ws + 88080384);    // 2048*9216 (v region unused)
    f16* qbuf   = (f16*)(ws + 125829120);   // 24*2048*128
    f16* kbuf   = (f16*)(ws + 138412032);   // 24*2048*128
    f16* vT     = (f16*)(ws + 150994944);   // 24*128*2048
    f16* attnb  = (f16*)(ws + 163577856);   // 2048*3072
    if (ws_size < 176160768) return;

    cvt3_kernel<<<2048, 256, 0, stream>>>(x, xb, (2048 * 3072) / 4,
                                          w_qkv, wqkvb, (9216 * 3072) / 4,
                                          w_proj, wprojb, (3072 * 3072) / 4);

    // qkv GEMM (R5 256x128 shape, best measured) with fused V-transpose
    qkv_gemm<<<dim3(72, 8), 512, 0, stream>>>(xb, wqkvb, qkvb, vT, 2048, 9216, 3072);
    fuse_qk_kernel<<<dim3(2048, 6), 256, 0, stream>>>(qkvb, pe, q_scale, k_scale, qbuf, kbuf);
    attn_kernel<<<dim3(16, 24), 256, 0, stream>>>(qbuf, kbuf, vT, attnb);
    proj_gemm<<<dim3(24, 16), 256, 0, stream>>>(attnb, wprojb, out, b_proj,
                                                2048, 3072, 3072);
}

// Round 22
// 341.262 us; speedup vs baseline: 1.0364x; 1.0364x over previous
//
#include <hip/hip_runtime.h>
#include <hip/hip_bf16.h>

typedef _Float16 f16;
typedef _Float16 f16x2 __attribute__((ext_vector_type(2)));
typedef _Float16 f16x4 __attribute__((ext_vector_type(4)));
typedef _Float16 f16x8 __attribute__((ext_vector_type(8)));
typedef float f32x4 __attribute__((ext_vector_type(4)));

#define L_SEQ 2048
#define DIM 3072
#define NHEAD 24
#define HDIM 128

// async global->LDS, 16B per lane. LDS dest must be wave-uniform base (+lane*16 implicit).
__device__ __forceinline__ void gll16(const f16* g, f16* l) {
    __builtin_amdgcn_global_load_lds((const __attribute__((address_space(1))) void*)g,
                                     (__attribute__((address_space(3))) void*)l, 16, 0, 0);
}

// ---------------- merged f32 -> f16 conversion (3 regions, 1 launch) --------
__global__ __launch_bounds__(256) void cvt3_kernel(const float* __restrict__ s0, f16* __restrict__ d0, int n0,
                                                   const float* __restrict__ s1, f16* __restrict__ d1, int n1,
                                                   const float* __restrict__ s2, f16* __restrict__ d2, int n2) {
    int i = blockIdx.x * blockDim.x + threadIdx.x;
    int stride = gridDim.x * blockDim.x;
    for (int j = i; j < n0; j += stride) {
        float4 v = reinterpret_cast<const float4*>(s0)[j];
        f16x4 o = {(f16)v.x, (f16)v.y, (f16)v.z, (f16)v.w};
        reinterpret_cast<f16x4*>(d0)[j] = o;
    }
    for (int j = i; j < n1; j += stride) {
        float4 v = reinterpret_cast<const float4*>(s1)[j];
        f16x4 o = {(f16)v.x, (f16)v.y, (f16)v.z, (f16)v.w};
        reinterpret_cast<f16x4*>(d1)[j] = o;
    }
    for (int j = i; j < n2; j += stride) {
        float4 v = reinterpret_cast<const float4*>(s2)[j];
        f16x4 o = {(f16)v.x, (f16)v.y, (f16)v.z, (f16)v.w};
        reinterpret_cast<f16x4*>(d2)[j] = o;
    }
}

// ---------------- 128x128-tile ring-3 NT GEMM (R12/R17-proven best) ---------
#define GEMM_BODY_S(T, VM, DO_STAGE)                                                    \
    {                                                                                   \
        asm volatile("s_waitcnt vmcnt(" #VM ")" ::: "memory");                          \
        __builtin_amdgcn_s_barrier();                                                   \
        __builtin_amdgcn_sched_barrier(0);                                              \
        const int slot_ = (T) % 3;                                                      \
        f16x8 af[4], bf[4];                                                             \
        _Pragma("unroll") for (int i = 0; i < 4; i++)                                   \
            af[i] = *reinterpret_cast<const f16x8*>(                                    \
                &As[slot_][(wr + i * 16 + laneM) * 32 + fc16]);                         \
        _Pragma("unroll") for (int j = 0; j < 4; j++)                                   \
            bf[j] = *reinterpret_cast<const f16x8*>(                                    \
                &Bs[slot_][(wc + j * 16 + laneM) * 32 + fc16]);                         \
        if (DO_STAGE) {                                                                 \
            const int t2 = (T) + 2;                                                     \
            const int s2 = t2 % 3;                                                      \
            gll16(Asrc + t2 * 32, &As[s2][dstoff]);                                     \
            gll16(Asrc + (size_t)64 * K + t2 * 32, &As[s2][2048 + dstoff]);             \
            gll16(Bsrc + t2 * 32, &Bs[s2][dstoff]);                                     \
            gll16(Bsrc + (size_t)64 * K + t2 * 32, &Bs[s2][2048 + dstoff]);             \
        }                                                                               \
        __builtin_amdgcn_s_setprio(1);                                                  \
        _Pragma("unroll") for (int i = 0; i < 4; i++)                                   \
            _Pragma("unroll") for (int j = 0; j < 4; j++)                               \
                acc[i][j] =                                                             \
                    __builtin_amdgcn_mfma_f32_16x16x32_f16(af[i], bf[j], acc[i][j],     \
                                                           0, 0, 0);                    \
        __builtin_amdgcn_s_setprio(0);                                                  \
    }

template <int MODE>
__global__ __launch_bounds__(256, 4) void rg128_gemm(const f16* __restrict__ A,
                                                     const f16* __restrict__ B,
                                                     f16* __restrict__ Cf16,
                                                     f16* __restrict__ vT,
                                                     float* __restrict__ Cf32,
                                                     const float* __restrict__ bias,
                                                     int M, int N, int K) {
    __shared__ f16 As[3][128 * 32];   // 3 x 8 KB
    __shared__ f16 Bs[3][128 * 32];   // 3 x 8 KB
    const int tid = threadIdx.x;
    const int wid = tid >> 6;
    const int lane = tid & 63;
    const int grp = lane >> 4;
    const int laneM = lane & 15;

    const int nwg = gridDim.x * gridDim.y;
    const int orig = blockIdx.y * gridDim.x + blockIdx.x;
    const int wgid = (orig & 7) * (nwg >> 3) + (orig >> 3);
    const int by = wgid % gridDim.y;
    const int bx = wgid / gridDim.y;
    const int m0 = by * 128;
    const int n0 = bx * 128;

    const int wr = (wid >> 1) * 64;
    const int wc = (wid & 1) * 64;
    const int NT = K >> 5;
    const int fc16 = (grp ^ ((laneM >> 1) & 3)) * 8;

    const int srow = tid >> 2;
    const int scol = (((tid & 3) ^ ((tid >> 3) & 3)) << 3);
    const f16* Asrc = A + (size_t)(m0 + srow) * K + scol;
    const f16* Bsrc = B + (size_t)(n0 + srow) * K + scol;
    const int dstoff = wid * 512;

    const f32x4 vzero = {0.f, 0.f, 0.f, 0.f};
    f32x4 acc[4][4];
#pragma unroll
    for (int i = 0; i < 4; i++)
#pragma unroll
        for (int j = 0; j < 4; j++) acc[i][j] = vzero;

#pragma unroll
    for (int t = 0; t < 2; t++) {
        gll16(Asrc + t * 32, &As[t][dstoff]);
        gll16(Asrc + (size_t)64 * K + t * 32, &As[t][2048 + dstoff]);
        gll16(Bsrc + t * 32, &Bs[t][dstoff]);
        gll16(Bsrc + (size_t)64 * K + t * 32, &Bs[t][2048 + dstoff]);
    }

    int t = 0;
    for (; t < NT - 2; ++t) GEMM_BODY_S(t, 4, true);
    GEMM_BODY_S(t, 4, false); ++t;
    GEMM_BODY_S(t, 0, false);

    // epilogue: C/D layout col = laneM, row = grp*4 + r (verified m89)
    if (MODE == 1) {
#pragma unroll
        for (int i = 0; i < 4; i++)
#pragma unroll
            for (int j = 0; j < 4; j++)
#pragma unroll
                for (int r = 0; r < 4; r++) {
                    int row = m0 + wr + i * 16 + grp * 4 + r;
                    int col = n0 + wc + j * 16 + laneM;
                    Cf32[(size_t)row * N + col] = acc[i][j][r] + bias[col];
                }
    } else if (n0 < 2 * DIM) {
#pragma unroll
        for (int i = 0; i < 4; i++)
#pragma unroll
            for (int j = 0; j < 4; j++)
#pragma unroll
                for (int r = 0; r < 4; r++) {
                    int row = m0 + wr + i * 16 + grp * 4 + r;
                    int col = n0 + wc + j * 16 + laneM;
                    Cf16[(size_t)row * N + col] = (f16)acc[i][j][r];
                }
    } else {
        // v columns: fused transpose -> vT[hd][l], 4 consecutive l per lane (8B)
#pragma unroll
        for (int i = 0; i < 4; i++)
#pragma unroll
            for (int j = 0; j < 4; j++) {
                int hd = n0 - 2 * DIM + wc + j * 16 + laneM;
                int row0 = m0 + wr + i * 16 + grp * 4;
                f16x4 pk;
#pragma unroll
                for (int r = 0; r < 4; r++) pk[r] = (f16)acc[i][j][r];
                *reinterpret_cast<f16x4*>(&vT[(size_t)hd * L_SEQ + row0]) = pk;
            }
    }
}

// ---------------- fused RMSNorm + RoPE for q,k (4 waves = 4 heads/block) ----
__global__ __launch_bounds__(256) void fuse_qk_kernel(const f16* __restrict__ qkv,
                                                      const float* __restrict__ pe,
                                                      const float* __restrict__ qs,
                                                      const float* __restrict__ ks,
                                                      f16* __restrict__ qb,
                                                      f16* __restrict__ kb) {
    const int l = blockIdx.x;
    const int h = blockIdx.y * 4 + (threadIdx.x >> 6);
    const int i = threadIdx.x & 63;
    const f16* row = qkv + (size_t)l * (3 * DIM) + h * HDIM;
    f16x2 qp = *reinterpret_cast<const f16x2*>(row + 2 * i);
    f16x2 kp = *reinterpret_cast<const f16x2*>(row + DIM + 2 * i);
    float q0 = (float)qp[0], q1 = (float)qp[1];
    float k0 = (float)kp[0], k1 = (float)kp[1];
    float sq = q0 * q0 + q1 * q1;
    float sk = k0 * k0 + k1 * k1;
#pragma unroll
    for (int off = 1; off < 64; off <<= 1) {
        sq += __shfl_xor(sq, off);
        sk += __shfl_xor(sk, off);
    }
    const float SCALE = 0.08838834764831845f;  // 1/sqrt(128), folded into q
    float rq = rsqrtf(sq * (1.0f / 128.0f) + 1e-6f) * SCALE;
    float rk = rsqrtf(sk * (1.0f / 128.0f) + 1e-6f);
    float4 w = *reinterpret_cast<const float4*>(pe + ((size_t)l * 64 + i) * 4);
    float qa = q0 * rq * qs[2 * i];
    float qbv = q1 * rq * qs[2 * i + 1];
    float ka = k0 * rk * ks[2 * i];
    float kbv = k1 * rk * ks[2 * i + 1];
    f16x2 qo = {(f16)(w.x * qa + w.y * qbv), (f16)(w.z * qa + w.w * qbv)};
    f16x2 ko = {(f16)(w.x * ka + w.y * kbv), (f16)(w.z * ka + w.w * kbv)};
    *reinterpret_cast<f16x2*>(qb + ((size_t)h * L_SEQ + l) * HDIM + 2 * i) = qo;
    *reinterpret_cast<f16x2*>(kb + ((size_t)h * L_SEQ + l) * HDIM + 2 * i) = ko;
}

// ---------------- flash attention v2: 32 q-rows per wave (R20-proven) -------
#define KVBLK 64
#define NSTEP (L_SEQ / KVBLK)

__device__ __forceinline__ void stage_kv(const f16* __restrict__ Kh,
                                         const f16* __restrict__ Vh,
                                         int k0, f16* Kt, f16* Vt, int tid) {
    const int wid = tid >> 6;
    const int krow = tid >> 4;
    const int kcl = (tid & 15) ^ (krow & 7);
    const int vrow = tid >> 3;
    const int vcl = (tid & 7) ^ (vrow & 7);
#pragma unroll
    for (int i = 0; i < 4; i++)
        gll16(Kh + (size_t)(k0 + i * 16 + krow) * HDIM + kcl * 8, Kt + i * 2048 + wid * 512);
#pragma unroll
    for (int i = 0; i < 4; i++)
        gll16(Vh + (size_t)(i * 32 + vrow) * L_SEQ + k0 + vcl * 8, Vt + i * 2048 + wid * 512);
}

__global__ __launch_bounds__(256, 2) void attn_kernel(const f16* __restrict__ qb,
                                                      const f16* __restrict__ kb,
                                                      const f16* __restrict__ vT,
                                                      f16* __restrict__ attnb) {
    __shared__ f16 Kt[2][64 * 128];   // 2 x 16 KB
    __shared__ f16 Vt[2][128 * 64];   // 2 x 16 KB
    __shared__ f16 Pl[4][16 * 72];    // per-wave P tile (reused for both groups)
    const int tid = threadIdx.x;
    const int wid = tid >> 6;
    const int lane = tid & 63;
    const int grp = lane >> 4;
    const int laneM = lane & 15;

    // T1: bijective XCD chunk (nwg = 384, %8 == 0). Same-head blocks cluster.
    const int nwg = gridDim.x * gridDim.y;
    const int orig = blockIdx.y * gridDim.x + blockIdx.x;
    const int wgid = (orig & 7) * (nwg >> 3) + (orig >> 3);
    const int h = wgid / gridDim.x;
    const int q0 = (wgid % gridDim.x) * 128 + wid * 32;   // 32 q-rows per wave

    const f16* Qh = qb + (size_t)h * L_SEQ * HDIM;
    const f16* Kh = kb + (size_t)h * L_SEQ * HDIM;
    const f16* Vh = vT + (size_t)h * HDIM * L_SEQ;

    f16x8 qf[2][4];
#pragma unroll
    for (int g = 0; g < 2; g++)
#pragma unroll
        for (int c = 0; c < 4; c++)
            qf[g][c] = *reinterpret_cast<const f16x8*>(
                Qh + (size_t)(q0 + g * 16 + laneM) * HDIM + c * 32 + grp * 8);

    const f32x4 vzero = {0.f, 0.f, 0.f, 0.f};
    f32x4 O[2][8];
#pragma unroll
    for (int g = 0; g < 2; g++)
#pragma unroll
        for (int f = 0; f < 8; f++) O[g][f] = vzero;
    float m[2] = {-3.0e38f, -3.0e38f};
    float lsum[2] = {0.f, 0.f};
    f16* Prow = &Pl[wid][laneM * 72];
    const int swz = laneM & 7;

    stage_kv(Kh, Vh, 0, Kt[0], Vt[0], tid);

    for (int step = 0; step < NSTEP; ++step) {
        const int cur = step & 1;
        __syncthreads();
        if (step + 1 < NSTEP)
            stage_kv(Kh, Vh, (step + 1) * KVBLK, Kt[cur ^ 1], Vt[cur ^ 1], tid);
        const f16* Kc = Kt[cur];
        const f16* Vc = Vt[cur];

        f32x4 s[2][4];
#pragma unroll
        for (int g = 0; g < 2; g++)
#pragma unroll
            for (int cc = 0; cc < 4; cc++) s[g][cc] = vzero;
#pragma unroll
        for (int cc = 0; cc < 4; cc++) {
            f16x8 kf[4];
#pragma unroll
            for (int c = 0; c < 4; c++)
                kf[c] = *reinterpret_cast<const f16x8*>(
                    &Kc[(cc * 16 + laneM) * 128 + (((c * 4 + grp) ^ swz) * 8)]);
#pragma unroll
            for (int c = 0; c < 4; c++) {
                s[0][cc] = __builtin_amdgcn_mfma_f32_16x16x32_f16(kf[c], qf[0][c], s[0][cc], 0, 0, 0);
                s[1][cc] = __builtin_amdgcn_mfma_f32_16x16x32_f16(kf[c], qf[1][c], s[1][cc], 0, 0, 0);
            }
        }

#pragma unroll
        for (int g = 0; g < 2; g++) {
            float pmax = s[g][0][0];
#pragma unroll
            for (int cc = 0; cc < 4; cc++)
#pragma unroll
                for (int r = 0; r < 4; r++) pmax = fmaxf(pmax, s[g][cc][r]);
            if (!__all(pmax <= m[g] + 8.0f)) {  // defer-max
                float pm = fmaxf(pmax, __shfl_xor(pmax, 16));
                pm = fmaxf(pm, __shfl_xor(pm, 32));
                float mnew = fmaxf(m[g], pm);
                float alpha = __expf(m[g] - mnew);
                m[g] = mnew;
                lsum[g] *= alpha;
                float af[4];
#pragma unroll
                for (int r = 0; r < 4; r++) af[r] = __shfl(alpha, grp * 4 + r);
#pragma unroll
                for (int f = 0; f < 8; f++)
#pragma unroll
                    for (int r = 0; r < 4; r++) O[g][f][r] *= af[r];
            }
            float ps = 0.f;
#pragma unroll
            for (int cc = 0; cc < 4; cc++) {
                f16x4 pk;
#pragma unroll
                for (int r = 0; r < 4; r++) {
                    float p = __expf(s[g][cc][r] - m[g]);
                    ps += p;
                    pk[r] = (f16)p;
                }
                *reinterpret_cast<f16x4*>(Prow + cc * 16 + grp * 4) = pk;
            }
            ps += __shfl_xor(ps, 16);
            ps += __shfl_xor(ps, 32);
            lsum[g] += ps;

#pragma unroll
            for (int z = 0; z < 2; z++) {
                f16x8 pa = *reinterpret_cast<const f16x8*>(Prow + z * 32 + grp * 8);
#pragma unroll
                for (int f = 0; f < 8; f++) {
                    f16x8 vf = *reinterpret_cast<const f16x8*>(
                        &Vc[(f * 16 + laneM) * 64 + (((z * 4 + grp) ^ swz) * 8)]);
                    O[g][f] = __builtin_amdgcn_mfma_f32_16x16x32_f16(pa, vf, O[g][f], 0, 0, 0);
                }
            }
        }
    }

#pragma unroll
    for (int g = 0; g < 2; g++) {
        float li = 1.0f / lsum[g];
        float lf[4];
#pragma unroll
        for (int r = 0; r < 4; r++) lf[r] = __shfl(li, grp * 4 + r);
#pragma unroll
        for (int f = 0; f < 8; f++)
#pragma unroll
            for (int r = 0; r < 4; r++) {
                int row = q0 + g * 16 + grp * 4 + r;
                attnb[(size_t)row * DIM + h * HDIM + f * 16 + laneM] = (f16)(O[g][f][r] * lf[r]);
            }
    }
}

extern "C" void kernel_launch(void* const* d_in, const int* in_sizes, int n_in,
                              void* d_out, int out_size, void* d_ws, size_t ws_size,
                              hipStream_t stream) {
    const float* x = (const float*)d_in[0];
    const float* pe = (const float*)d_in[1];
    const float* w_qkv = (const float*)d_in[2];
    const float* w_proj = (const float*)d_in[3];
    const float* b_proj = (const float*)d_in[4];
    const float* q_scale = (const float*)d_in[5];
    const float* k_scale = (const float*)d_in[6];
    float* out = (float*)d_out;

    char* ws = (char*)d_ws;
    f16* xb     = (f16*)(ws + 0);           // 2048*3072
    f16* wqkvb  = (f16*)(ws + 12582912);    // 9216*3072
    f16* wprojb = (f16*)(ws + 69206016);    // 3072*3072
    f16* qkvb   = (f16*)(ws + 88080384);    // 2048*9216 (v region unused)
    f16* qbuf   = (f16*)(ws + 125829120);   // 24*2048*128
    f16* kbuf   = (f16*)(ws + 138412032);   // 24*2048*128
    f16* vT     = (f16*)(ws + 150994944);   // 24*128*2048
    f16* attnb  = (f16*)(ws + 163577856);   // 2048*3072
    if (ws_size < 176160768) return;

    cvt3_kernel<<<2048, 256, 0, stream>>>(x, xb, (2048 * 3072) / 4,
                                          w_qkv, wqkvb, (9216 * 3072) / 4,
                                          w_proj, wprojb, (3072 * 3072) / 4);

    rg128_gemm<0><<<dim3(72, 16), 256, 0, stream>>>(xb, wqkvb, qkvb, vT, nullptr, nullptr,
                                                    2048, 9216, 3072);
    fuse_qk_kernel<<<dim3(2048, 6), 256, 0, stream>>>(qkvb, pe, q_scale, k_scale, qbuf, kbuf);
    attn_kernel<<<dim3(16, 24), 256, 0, stream>>>(qbuf, kbuf, vT, attnb);
    rg128_gemm<1><<<dim3(24, 16), 256, 0, stream>>>(attnb, wprojb, nullptr, nullptr, out, b_proj,
                                                    2048, 3072, 3072);
}